// Round 14
// baseline (348.630 us; speedup 1.0000x reference)
//
#include <hip/hip_runtime.h>
#include <cstdint>

// B=8, Cin=Cout=128, x 128x128 -> out 256x256.
#define SCALE_MAIN 0.029462782549439483f   // 1/sqrt(128*9)
#define LSCALE     0.044194173824159223f   // 1/sqrt(512)
#define CSCALE     0.029462782549439483f   // 1/sqrt(128*9)

typedef __attribute__((ext_vector_type(8))) short bf16x8;
typedef __attribute__((ext_vector_type(4))) float f32x4;
typedef __attribute__((ext_vector_type(2))) unsigned int u32x2;
typedef __attribute__((ext_vector_type(4))) unsigned int u32x4;

static __device__ __forceinline__ float lrelu_s2(float v) {
  return (v > 0.f ? v : 0.2f * v) * 1.4142135623730951f;
}
static __device__ __forceinline__ unsigned short f2bf(float f) {
  unsigned int u = __builtin_bit_cast(unsigned int, f);
  u += 0x7FFFu + ((u >> 16) & 1u);
  return (unsigned short)(u >> 16);
}
static __device__ __forceinline__ float lo16(unsigned int v) {
  return __builtin_bit_cast(float, v << 16);
}
static __device__ __forceinline__ float hi16(unsigned int v) {
  return __builtin_bit_cast(float, v & 0xFFFF0000u);
}
// rel even -> sc odd -> high half; rel odd -> low half. u32 index (rel+1)>>1.
#define EX(arr, rel) (((rel) & 1) ? lo16((arr)[((rel) + 1) >> 1]) : hi16((arr)[((rel) + 1) >> 1]))

// ---------------------------------------------------------------------------
// K1 prep_all (verified; NT loads on single-use x / lin_w streams)
// ---------------------------------------------------------------------------
__global__ __launch_bounds__(256) void prep_all(
    const float* __restrict__ weight, const float* __restrict__ cw_w,
    const float* __restrict__ cb_w, const float* __restrict__ x,
    const float* __restrict__ style, const float* __restrict__ lin_w,
    const float* __restrict__ lin_b, short* __restrict__ kbu,
    short* __restrict__ kb2, unsigned short* __restrict__ xt,
    unsigned short* __restrict__ smap_bf) {
  int bid = blockIdx.x;
  int t = threadIdx.x;
  if (bid < 2048) {
    int idx = bid * 256 + t;
    int j   = idx & 7;
    int co  = (idx >> 3) & 255;
    int kc  = (idx >> 11) & 63;
    int par = idx >> 17;
    int k = kc * 8 + j;
    int t2 = k >> 7, ci = k & 127;
    int dy2 = t2 >> 1, dx2 = t2 & 1;
    int ph = par >> 1, pw = par & 1;
    const float* wsrc = (co < 128)
        ? cw_w + ((size_t)co * 128 + ci) * 9
        : cb_w + ((size_t)(co - 128) * 128 + ci) * 9;
    float acc = 0.f;
    #pragma unroll
    for (int kh = 0; kh < 3; ++kh) {
      bool okh = dy2 == 0 ? (ph == 0 ? kh == 0 : kh <= 1)
                          : (ph == 0 ? kh >= 1 : kh == 2);
      if (!okh) continue;
      #pragma unroll
      for (int kw = 0; kw < 3; ++kw) {
        bool okw = dx2 == 0 ? (pw == 0 ? kw == 0 : kw <= 1)
                            : (pw == 0 ? kw >= 1 : kw == 2);
        if (okw) acc += wsrc[kh * 3 + kw];
      }
    }
    kb2[idx] = (short)f2bf(acc * CSCALE);
  } else if (bid < 2624) {
    int idx2 = (bid - 2048) * 256 + t;       // < 147456
    int j    = idx2 & 7;
    int co   = (idx2 >> 3) & 127;
    int ksub = (idx2 >> 10) & 3;
    int s    = (idx2 >> 12) & 3;
    int tp   = idx2 >> 14;                   // tap 0..8
    int ci = s * 32 + ksub * 8 + j;
    int wr = (tp == 0 || tp == 1 || tp == 4) ? 2
           : (tp >= 6) ? 1 : 0;
    int wc = (tp == 0 || tp == 2 || tp == 6) ? 2
           : (tp == 4 || tp == 5 || tp == 8) ? 1 : 0;
    float v = weight[((size_t)(co * 128 + ci)) * 9 + wr * 3 + wc] * SCALE_MAIN;
    kbu[idx2] = (short)f2bf(v);
  } else if (bid < 3648) {
    int q = bid - 2624;
    int y = q & 127, b = q >> 7;
    __shared__ unsigned short tl[128 * 134];
    #pragma unroll 4
    for (int i = 0; i < 16; ++i) {
      int c = t + i * 256;
      int ci = c >> 5, x4 = c & 31;
      f32x4 v = __builtin_nontemporal_load(
          (const f32x4*)(x + (size_t)(b * 128 + ci) * 16384 + y * 128 + x4 * 4));
      unsigned int* dst = (unsigned int*)(tl + ci * 134 + x4 * 4);
      dst[0] = (unsigned int)f2bf(v.x) | ((unsigned int)f2bf(v.y) << 16);
      dst[1] = (unsigned int)f2bf(v.z) | ((unsigned int)f2bf(v.w) << 16);
    }
    __syncthreads();
    #pragma unroll 2
    for (int i = 0; i < 8; ++i) {
      int c = t + i * 256;
      int xcol = c >> 4, sub = c & 15;
      unsigned short u[8];
      #pragma unroll
      for (int j = 0; j < 8; ++j) u[j] = tl[(sub * 8 + j) * 134 + xcol];
      u32x4 o;
      o.x = (unsigned int)u[0] | ((unsigned int)u[1] << 16);
      o.y = (unsigned int)u[2] | ((unsigned int)u[3] << 16);
      o.z = (unsigned int)u[4] | ((unsigned int)u[5] << 16);
      o.w = (unsigned int)u[6] | ((unsigned int)u[7] << 16);
      *(u32x4*)(xt + ((size_t)(b * 128 + y) * 128 + xcol) * 128 + sub * 8) = o;
    }
  } else {
    int wid = t >> 6, lane = t & 63;
    int gw = (bid - 3648) * 4 + wid;
    const float4* st4 = (const float4*)style;
    float s[8][8];
    #pragma unroll
    for (int b = 0; b < 8; ++b) {
      float4 a0 = st4[b * 128 + lane * 2];
      float4 a1 = st4[b * 128 + lane * 2 + 1];
      s[b][0] = a0.x; s[b][1] = a0.y; s[b][2] = a0.z; s[b][3] = a0.w;
      s[b][4] = a1.x; s[b][5] = a1.y; s[b][6] = a1.z; s[b][7] = a1.w;
    }
    for (int rr = 0; rr < 16; ++rr) {
      int j = gw * 16 + rr;
      const f32x4* wp = (const f32x4*)(lin_w + (size_t)j * 512);
      f32x4 w0 = __builtin_nontemporal_load(wp + lane * 2);
      f32x4 w1 = __builtin_nontemporal_load(wp + lane * 2 + 1);
      float acc[8];
      #pragma unroll
      for (int b = 0; b < 8; ++b) {
        acc[b] = w0.x * s[b][0] + w0.y * s[b][1] + w0.z * s[b][2] + w0.w * s[b][3]
               + w1.x * s[b][4] + w1.y * s[b][5] + w1.z * s[b][6] + w1.w * s[b][7];
      }
      #pragma unroll
      for (int m = 32; m; m >>= 1) {
        #pragma unroll
        for (int b = 0; b < 8; ++b) acc[b] += __shfl_xor(acc[b], m, 64);
      }
      if (lane == 0) {
        float bias = lin_b[j];
        int ci = j >> 8, sp = j & 255;
        #pragma unroll
        for (int b = 0; b < 8; ++b)
          smap_bf[(size_t)(b * 256 + sp) * 128 + ci] =
              f2bf(lrelu_s2(acc[b] * LSCALE + bias));
      }
    }
  }
}

// ---------------------------------------------------------------------------
// K2 modconv (verbatim -- verified)
// ---------------------------------------------------------------------------
__global__ __launch_bounds__(512, 2) void modconv_kernel(
    const unsigned short* __restrict__ smap_bf, const short* __restrict__ kb2,
    const float* __restrict__ cw_b, const float* __restrict__ cb_b,
    float* __restrict__ swp) {
  extern __shared__ __align__(16) char dsm[];   // 73984 B
  int par = blockIdx.x, b = blockIdx.y;
  int ph = par >> 1, pw = par & 1;
  int t = threadIdx.x, lane = t & 63, w = t >> 6;
  int q = w >> 1, ch = w & 1;
  int m15 = lane & 15, ksub = lane >> 4;

  for (int c = t; c < 4624; c += 512) {
    int s = c >> 4, cch = c & 15;
    int rr = s / 17, cc = s - rr * 17;
    int gr = rr - 1 + ph, gc = cc - 1 + pw;
    u32x4 v = {0u, 0u, 0u, 0u};
    if ((unsigned)gr < 16u && (unsigned)gc < 16u)
      v = *(const u32x4*)(smap_bf + ((size_t)(b * 256 + gr * 16 + gc) * 128 + cch * 8));
    int phys = (cch + s) & 15;
    *(u32x4*)(dsm + s * 256 + phys * 16) = v;
  }
  __syncthreads();

  const bf16x8* kbv = (const bf16x8*)kb2;
  f32x4 acc[4][8];
  #pragma unroll
  for (int i = 0; i < 4; ++i)
  #pragma unroll
  for (int j = 0; j < 8; ++j) acc[i][j] = (f32x4){0.f, 0.f, 0.f, 0.f};

  for (int s = 0; s < 16; ++s) {
    int t2 = s >> 2, dy2 = t2 >> 1, dx2 = t2 & 1;
    int cch = (s & 3) * 4 + ksub;
    bf16x8 av[4];
    #pragma unroll
    for (int mf = 0; mf < 4; ++mf) {
      int i = q * 4 + mf;
      int ssp = (i + dy2) * 17 + (m15 + dx2);
      int phys = (cch + ssp) & 15;
      av[mf] = *(const bf16x8*)(dsm + ssp * 256 + phys * 16);
    }
    #pragma unroll
    for (int nf = 0; nf < 8; ++nf) {
      bf16x8 bv = kbv[(size_t)((par * 64 + s * 4 + ksub) * 256 + ch * 128 + nf * 16 + m15)];
      #pragma unroll
      for (int mf = 0; mf < 4; ++mf)
        acc[mf][nf] = __builtin_amdgcn_mfma_f32_16x16x32_bf16(av[mf], bv, acc[mf][nf], 0, 0, 0);
    }
  }

  int jbase = ksub * 4;
  #pragma unroll
  for (int nf = 0; nf < 8; ++nf) {
    int co = ch * 128 + nf * 16 + m15;
    float bias = (co < 128) ? cw_b[co] : cb_b[co - 128];
    #pragma unroll
    for (int mf = 0; mf < 4; ++mf) {
      int i = q * 4 + mf;
      #pragma unroll
      for (int r = 0; r < 4; ++r) {
        int px = i * 16 + jbase + r;
        swp[((size_t)(b * 256 + co) * 4 + par) * 256 + px] = acc[mf][nf][r] + bias;
      }
    }
  }
}

// ---------------------------------------------------------------------------
// K3 convt v3b: verified r12 structure; cg==4 blocks skip odd-mf loads/MFMA
// (only even-mf eps entries are ever stored there -- proof: store guard
// ch==0 -> pxq=pr*8 -> mf=pr*2 even). Bit-identical output.
// ---------------------------------------------------------------------------
__global__ __launch_bounds__(256, 2) void convt_kernel(
    const unsigned short* __restrict__ xt, const short* __restrict__ kbu,
    unsigned short* __restrict__ out1) {
  __shared__ __align__(16) char smem[34816];   // A-tile 26112; eps 34816
  int cg = blockIdx.x, rp = blockIdx.y, b = blockIdx.z;
  int t = threadIdx.x, lane = t & 63, w = t >> 6;
  int m15 = lane & 15, ksub = lane >> 4;
  int pl = (w + cg + rp) & 3;                  // wave's plane, SIMD-balanced
  int tstart = (pl == 0) ? 0 : 2 + 2 * pl;     // {0,4,6,8}
  int nst = 16 >> ((pl + 1) >> 1);             // {16,8,8,4}
  bool cg4 = (cg == 4);

  const char* xtc = (const char*)xt;
  for (int c = t; c < 1632; c += 256) {
    int spos = c >> 4, sub = c & 15;
    int lr = spos / 34, lc = spos - lr * 34;
    int y = 2 * rp - 1 + lr, xg = 32 * cg - 1 + lc;
    f32x4 v = {0.f, 0.f, 0.f, 0.f};
    if ((unsigned)y < 128u && (unsigned)xg < 128u)
      v = *(const f32x4*)(xtc + ((size_t)((b * 128 + y) * 128 + xg)) * 256 + sub * 16);
    int phys = (sub & 8) | ((sub ^ spos) & 7);
    *(f32x4*)(smem + spos * 256 + phys * 16) = v;
  }
  __syncthreads();

  const bf16x8* kbv = (const bf16x8*)kbu;
  f32x4 acc[4][8];
  #pragma unroll
  for (int i = 0; i < 4; ++i)
  #pragma unroll
  for (int j = 0; j < 8; ++j) acc[i][j] = (f32x4){0.f, 0.f, 0.f, 0.f};

  auto LD = [&](int s, bf16x8* av, bf16x8* bv) {
    int tap = tstart + (s >> 2);
    int du = -((0x13 >> tap) & 1);
    int dv = -((0x45 >> tap) & 1);
    int cc = s & 3;
    int c = cc * 4 + ksub;
    #pragma unroll
    for (int mf = 0; mf < 4; ++mf) {
      if (cg4 && (mf & 1)) continue;
      int spos = ((mf >> 1) + du + 1) * 34 + (mf & 1) * 16 + m15 + dv + 1;
      int phys = (c & 8) | ((c ^ spos) & 7);
      av[mf] = *(const bf16x8*)(smem + spos * 256 + phys * 16);
    }
    int bb = tap * 2048 + cc * 512 + ksub * 128 + m15;
    #pragma unroll
    for (int nf = 0; nf < 8; ++nf) bv[nf] = kbv[bb + nf * 16];
  };
  auto MM = [&](bf16x8* av, bf16x8* bv) {
    __builtin_amdgcn_s_setprio(1);
    #pragma unroll
    for (int nf = 0; nf < 8; ++nf)
    #pragma unroll
    for (int mf = 0; mf < 4; ++mf) {
      if (cg4 && (mf & 1)) continue;
      acc[mf][nf] = __builtin_amdgcn_mfma_f32_16x16x32_bf16(av[mf], bv[nf], acc[mf][nf], 0, 0, 0);
    }
    __builtin_amdgcn_s_setprio(0);
  };

  bf16x8 aA[4], bA[8], aB[4], bB[8];
  LD(0, aA, bA);
  for (int s = 0; s + 2 <= nst; s += 2) {
    LD(s + 1, aB, bB);
    MM(aA, bA);
    if (s + 2 < nst) LD(s + 2, aA, bA);
    MM(aB, bB);
  }

  __syncthreads();
  float* eps = (float*)smem;                   // [(pl*16+pxq)*2+e][68]
  int t63 = t & 63, wpl = t >> 6;
  #pragma unroll
  for (int r2 = 0; r2 < 4; ++r2) {
    #pragma unroll
    for (int e = 0; e < 2; ++e) {
      int nf = r2 * 2 + e;
      #pragma unroll
      for (int mf = 0; mf < 4; ++mf)
        *(f32x4*)(&eps[(((pl * 16 + mf * 4 + ksub) * 2 + e) * 68) + m15 * 4]) = acc[mf][nf];
    }
    __syncthreads();
    #pragma unroll
    for (int k = 0; k < 8; ++k) {
      int slot = k * 64 + t63;                 // [e:1][co16:4][pr:1][ch:3]
      int er = slot >> 8, co16 = (slot >> 4) & 15, pr = (slot >> 3) & 1, ch = slot & 7;
      f32x4 v = *(const f32x4*)(&eps[(((wpl * 16 + pr * 8 + ch) * 2 + er) * 68) + co16 * 4]);
      u32x2 o;
      o.x = (unsigned int)f2bf(v[0]) | ((unsigned int)f2bf(v[1]) << 16);
      o.y = (unsigned int)f2bf(v[2]) | ((unsigned int)f2bf(v[3]) << 16);
      int co = (r2 * 2 + er) * 16 + co16;
      int r = 2 * rp + pr;
      size_t ob = (((size_t)(b * 4 + wpl) * 128 + co) * 130 + r) * 132
                + 32 * cg + ch * 4;
      if (cg < 4 || ch == 0) *(u32x2*)(out1 + ob) = o;
    }
    __syncthreads();
  }
}

// ---------------------------------------------------------------------------
// K4/K5 blur v7: v6 stencil; PASS1 uses nontemporal out1 loads (last read)
// + nontemporal dout stores.
// ---------------------------------------------------------------------------
template <int PASS>
__global__ __launch_bounds__(256) void blur_kernel(
    const unsigned short* __restrict__ out1, float* __restrict__ part,
    const float* __restrict__ swp, float* __restrict__ dout) {
  __shared__ __align__(16) unsigned short S[18][4][144];
  __shared__ float lsw[4][32], lsb[4][32];
  __shared__ float msh[2];
  __shared__ float rb2[8];
  int g = blockIdx.x, co = blockIdx.y, b = blockIdx.z;
  int t = threadIdx.x, lane = t & 63, wid = t >> 6;
  int bc = b * 128 + co;

  if (PASS == 1) {
    if (t == 0) {
      float a1 = 0.f, a2 = 0.f;
      #pragma unroll
      for (int i = 0; i < 8; ++i) {
        a1 += part[((size_t)bc * 8 + i) * 2];
        a2 += part[((size_t)bc * 8 + i) * 2 + 1];
      }
      float mean = a1 * (1.f / 65536.f);
      float var = a2 * (1.f / 65536.f) - mean * mean;
      msh[0] = mean; msh[1] = rsqrtf(var + 1e-5f);
    }
    {
      int which = t >> 7;
      int par = (t >> 5) & 3;
      int idx = t & 31;
      int hrow = idx >> 4, wcol = idx & 15;
      int px2 = (2 * g + hrow) * 16 + wcol;
      float v = swp[((size_t)(b * 256 + which * 128 + co) * 4 + par) * 256 + px2];
      if (which == 0) lsw[par][idx] = v; else lsb[par][idx] = v;
    }
  }

  // ---- stage S: rows lr 0..17, 4 planes; fused 16B load + 16B LDS write ----
  int rbase = 16 * g - 1;
  for (int i = t; i < 1152; i += 256) {
    int rid = i >> 4, ch = i & 15;
    int lr = rid >> 2, pl = rid & 3;
    int r = rbase + lr;
    u32x4 v = {0u, 0u, 0u, 0u};
    if (r >= 0) {
      const u32x4* src =
          (const u32x4*)(out1 + ((size_t)((b * 4 + pl) * 128 + co) * 130 + r) * 132 + ch * 8);
      v = (PASS == 1) ? __builtin_nontemporal_load(src) : *src;
    }
    *(u32x4*)(&S[lr][pl][8 + ch * 8]) = v;
  }
  if (t < 72) {
    int lr = t >> 2, pl = t & 3;
    int r = rbase + lr;
    u32x2 v = {0u, 0u};
    if (r >= 0) {
      const u32x2* src =
          (const u32x2*)(out1 + ((size_t)((b * 4 + pl) * 128 + co) * 130 + r) * 132 + 128);
      v = (PASS == 1) ? __builtin_nontemporal_load(src) : *src;
    }
    *(u32x2*)(&S[lr][pl][136]) = v;
  }
  if (t >= 128 && t < 200) {
    int q = t - 128;
    *(unsigned int*)(&S[q >> 2][q & 3][6]) = 0u;
  }
  __syncthreads();

  float mean = 0.f, rstd = 0.f;
  if (PASS == 1) { mean = msh[0]; rstd = msh[1]; }

  int rg = t >> 5, cg = t & 31;
  int sr = 2 * rg;
  unsigned int Eu[2][3][4], Ou[2][4][4];
  #pragma unroll
  for (int cp = 0; cp < 2; ++cp) {
    #pragma unroll
    for (int rr = 0; rr < 3; ++rr) {
      const unsigned int* p = (const unsigned int*)&S[sr + 1 + rr][cp][0];
      #pragma unroll
      for (int j = 0; j < 4; ++j) Eu[cp][rr][j] = p[2 * cg + 3 + j];
    }
    #pragma unroll
    for (int rr = 0; rr < 4; ++rr) {
      const unsigned int* p = (const unsigned int*)&S[sr + rr][2 + cp][0];
      #pragma unroll
      for (int j = 0; j < 4; ++j) Ou[cp][rr][j] = p[2 * cg + 3 + j];
    }
  }

  float s1 = 0.f, s2 = 0.f;
  #pragma unroll
  for (int k = 0; k < 4; ++k) {
    const int a = (k + 1) >> 1;
    float Tc[2][6];
    #pragma unroll
    for (int cp = 0; cp < 2; ++cp)
    #pragma unroll
    for (int rel = 0; rel < 6; ++rel) {
      float v;
      if ((k & 1) == 0)
        v = EX(Ou[cp][a], rel) + 3.f * EX(Eu[cp][a], rel)
          + 3.f * EX(Ou[cp][a + 1], rel) + EX(Eu[cp][a + 1], rel);
      else
        v = EX(Eu[cp][a - 1], rel) + 3.f * EX(Ou[cp][a], rel)
          + 3.f * EX(Eu[cp][a], rel) + EX(Ou[cp][a + 1], rel);
      Tc[cp][rel] = v;
    }
    float o8[8];
    #pragma unroll
    for (int i = 0; i < 4; ++i) {
      float ve = ((Tc[1][i] + Tc[0][i + 2]) + 3.f * (Tc[0][i + 1] + Tc[1][i + 1])) * 0.0625f;
      float vo = ((Tc[0][i + 1] + Tc[1][i + 2]) + 3.f * (Tc[1][i + 1] + Tc[0][i + 2])) * 0.0625f;
      if (PASS == 0) {
        s1 += ve + vo; s2 += ve * ve + vo * vo;
      } else {
        o8[2 * i] = ve; o8[2 * i + 1] = vo;
      }
    }
    if (PASS == 1) {
      int hl = 4 * rg + k;
      int h = 32 * g + hl;
      int par = ((hl >> 3) & 1) * 2 + (cg & 1);
      int lidx = ((hl >> 4) & 1) * 16 + (cg >> 1);
      float f1 = (1.f + 0.3f * lsw[par][lidx]) * rstd;
      float f0 = 0.3f * lsb[par][lidx] - mean * f1;
      f32x4 oA = {o8[0] * f1 + f0, o8[1] * f1 + f0, o8[2] * f1 + f0, o8[3] * f1 + f0};
      f32x4 oB = {o8[4] * f1 + f0, o8[5] * f1 + f0, o8[6] * f1 + f0, o8[7] * f1 + f0};
      float* op = dout + ((size_t)bc * 256 + h) * 256 + 8 * cg;
      __builtin_nontemporal_store(oA, (f32x4*)op);
      __builtin_nontemporal_store(oB, (f32x4*)(op + 4));
    }
  }

  if (PASS == 0) {
    #pragma unroll
    for (int m = 32; m; m >>= 1) { s1 += __shfl_xor(s1, m, 64); s2 += __shfl_xor(s2, m, 64); }
    if (lane == 0) { rb2[wid * 2] = s1; rb2[wid * 2 + 1] = s2; }
    __syncthreads();
    if (t == 0) {
      part[((size_t)bc * 8 + g) * 2]     = rb2[0] + rb2[2] + rb2[4] + rb2[6];
      part[((size_t)bc * 8 + g) * 2 + 1] = rb2[1] + rb2[3] + rb2[5] + rb2[7];
    }
  }
}

extern "C" void kernel_launch(void* const* d_in, const int* in_sizes, int n_in,
                              void* d_out, int out_size, void* d_ws, size_t ws_size,
                              hipStream_t stream) {
  const float* x      = (const float*)d_in[0];
  const float* style  = (const float*)d_in[1];
  const float* weight = (const float*)d_in[2];
  const float* lin_w  = (const float*)d_in[3];
  const float* lin_b  = (const float*)d_in[4];
  const float* cw_w   = (const float*)d_in[5];
  const float* cw_b   = (const float*)d_in[6];
  const float* cb_w   = (const float*)d_in[7];
  const float* cb_b   = (const float*)d_in[8];
  float* out = (float*)d_out;
  char* ws = (char*)d_ws;

  short*          kbu     = (short*)(ws);                     //   294,912
  short*          kb2     = (short*)(ws + 294912);            // 1,048,576
  unsigned short* xt      = (unsigned short*)(ws + 1343488);  // 33,554,432
  unsigned short* smap_bf = (unsigned short*)(ws + 34897920); //   524,288
  float*          swp     = (float*)(ws + 35422208);          // 8,388,608
  float*          part    = (float*)(ws + 43810816);          //   131,072
  unsigned short* out1    = (unsigned short*)(ws + 43941888); // 140,574,720 (end 184.5MB)

  prep_all<<<dim3(4160), dim3(256), 0, stream>>>(
      weight, cw_w, cb_w, x, style, lin_w, lin_b, kbu, kb2, xt, smap_bf);
  modconv_kernel<<<dim3(4, 8), dim3(512), 73984, stream>>>(smap_bf, kb2, cw_b, cb_b, swp);
  convt_kernel<<<dim3(5, 65, 8), dim3(256), 0, stream>>>(xt, kbu, out1);
  blur_kernel<0><<<dim3(8, 128, 8), dim3(256), 0, stream>>>(out1, part, swp, out);
  blur_kernel<1><<<dim3(8, 128, 8), dim3(256), 0, stream>>>(out1, part, swp, out);
}

// Round 15
// 332.496 us; speedup vs baseline: 1.0485x; 1.0485x over previous
//
#include <hip/hip_runtime.h>
#include <cstdint>

// B=8, Cin=Cout=128, x 128x128 -> out 256x256.
#define SCALE_MAIN 0.029462782549439483f   // 1/sqrt(128*9)
#define LSCALE     0.044194173824159223f   // 1/sqrt(512)
#define CSCALE     0.029462782549439483f   // 1/sqrt(128*9)

typedef __attribute__((ext_vector_type(8))) short bf16x8;
typedef __attribute__((ext_vector_type(4))) float f32x4;
typedef __attribute__((ext_vector_type(2))) unsigned int u32x2;
typedef __attribute__((ext_vector_type(4))) unsigned int u32x4;

static __device__ __forceinline__ float lrelu_s2(float v) {
  return (v > 0.f ? v : 0.2f * v) * 1.4142135623730951f;
}
static __device__ __forceinline__ unsigned short f2bf(float f) {
  unsigned int u = __builtin_bit_cast(unsigned int, f);
  u += 0x7FFFu + ((u >> 16) & 1u);
  return (unsigned short)(u >> 16);
}
static __device__ __forceinline__ float lo16(unsigned int v) {
  return __builtin_bit_cast(float, v << 16);
}
static __device__ __forceinline__ float hi16(unsigned int v) {
  return __builtin_bit_cast(float, v & 0xFFFF0000u);
}
// rel even -> sc odd -> high half; rel odd -> low half. u32 index (rel+1)>>1.
#define EX(arr, rel) (((rel) & 1) ? lo16((arr)[((rel) + 1) >> 1]) : hi16((arr)[((rel) + 1) >> 1]))

// ---------------------------------------------------------------------------
// K1 prep_all (verbatim r12 -- verified)
// ---------------------------------------------------------------------------
__global__ __launch_bounds__(256) void prep_all(
    const float* __restrict__ weight, const float* __restrict__ cw_w,
    const float* __restrict__ cb_w, const float* __restrict__ x,
    const float* __restrict__ style, const float* __restrict__ lin_w,
    const float* __restrict__ lin_b, short* __restrict__ kbu,
    short* __restrict__ kb2, unsigned short* __restrict__ xt,
    unsigned short* __restrict__ smap_bf) {
  int bid = blockIdx.x;
  int t = threadIdx.x;
  if (bid < 2048) {
    int idx = bid * 256 + t;
    int j   = idx & 7;
    int co  = (idx >> 3) & 255;
    int kc  = (idx >> 11) & 63;
    int par = idx >> 17;
    int k = kc * 8 + j;
    int t2 = k >> 7, ci = k & 127;
    int dy2 = t2 >> 1, dx2 = t2 & 1;
    int ph = par >> 1, pw = par & 1;
    const float* wsrc = (co < 128)
        ? cw_w + ((size_t)co * 128 + ci) * 9
        : cb_w + ((size_t)(co - 128) * 128 + ci) * 9;
    float acc = 0.f;
    #pragma unroll
    for (int kh = 0; kh < 3; ++kh) {
      bool okh = dy2 == 0 ? (ph == 0 ? kh == 0 : kh <= 1)
                          : (ph == 0 ? kh >= 1 : kh == 2);
      if (!okh) continue;
      #pragma unroll
      for (int kw = 0; kw < 3; ++kw) {
        bool okw = dx2 == 0 ? (pw == 0 ? kw == 0 : kw <= 1)
                            : (pw == 0 ? kw >= 1 : kw == 2);
        if (okw) acc += wsrc[kh * 3 + kw];
      }
    }
    kb2[idx] = (short)f2bf(acc * CSCALE);
  } else if (bid < 2624) {
    int idx2 = (bid - 2048) * 256 + t;       // < 147456
    int j    = idx2 & 7;
    int co   = (idx2 >> 3) & 127;
    int ksub = (idx2 >> 10) & 3;
    int s    = (idx2 >> 12) & 3;
    int tp   = idx2 >> 14;                   // tap 0..8
    int ci = s * 32 + ksub * 8 + j;
    int wr = (tp == 0 || tp == 1 || tp == 4) ? 2
           : (tp >= 6) ? 1 : 0;
    int wc = (tp == 0 || tp == 2 || tp == 6) ? 2
           : (tp == 4 || tp == 5 || tp == 8) ? 1 : 0;
    float v = weight[((size_t)(co * 128 + ci)) * 9 + wr * 3 + wc] * SCALE_MAIN;
    kbu[idx2] = (short)f2bf(v);
  } else if (bid < 3648) {
    int q = bid - 2624;
    int y = q & 127, b = q >> 7;
    __shared__ unsigned short tl[128 * 134];
    #pragma unroll 4
    for (int i = 0; i < 16; ++i) {
      int c = t + i * 256;
      int ci = c >> 5, x4 = c & 31;
      f32x4 v = *(const f32x4*)(x + (size_t)(b * 128 + ci) * 16384 + y * 128 + x4 * 4);
      unsigned int* dst = (unsigned int*)(tl + ci * 134 + x4 * 4);
      dst[0] = (unsigned int)f2bf(v.x) | ((unsigned int)f2bf(v.y) << 16);
      dst[1] = (unsigned int)f2bf(v.z) | ((unsigned int)f2bf(v.w) << 16);
    }
    __syncthreads();
    #pragma unroll 2
    for (int i = 0; i < 8; ++i) {
      int c = t + i * 256;
      int xcol = c >> 4, sub = c & 15;
      unsigned short u[8];
      #pragma unroll
      for (int j = 0; j < 8; ++j) u[j] = tl[(sub * 8 + j) * 134 + xcol];
      u32x4 o;
      o.x = (unsigned int)u[0] | ((unsigned int)u[1] << 16);
      o.y = (unsigned int)u[2] | ((unsigned int)u[3] << 16);
      o.z = (unsigned int)u[4] | ((unsigned int)u[5] << 16);
      o.w = (unsigned int)u[6] | ((unsigned int)u[7] << 16);
      *(u32x4*)(xt + ((size_t)(b * 128 + y) * 128 + xcol) * 128 + sub * 8) = o;
    }
  } else {
    int wid = t >> 6, lane = t & 63;
    int gw = (bid - 3648) * 4 + wid;
    const float4* st4 = (const float4*)style;
    float s[8][8];
    #pragma unroll
    for (int b = 0; b < 8; ++b) {
      float4 a0 = st4[b * 128 + lane * 2];
      float4 a1 = st4[b * 128 + lane * 2 + 1];
      s[b][0] = a0.x; s[b][1] = a0.y; s[b][2] = a0.z; s[b][3] = a0.w;
      s[b][4] = a1.x; s[b][5] = a1.y; s[b][6] = a1.z; s[b][7] = a1.w;
    }
    for (int rr = 0; rr < 16; ++rr) {
      int j = gw * 16 + rr;
      const float4* wp = (const float4*)(lin_w + (size_t)j * 512);
      float4 w0 = wp[lane * 2], w1 = wp[lane * 2 + 1];
      float acc[8];
      #pragma unroll
      for (int b = 0; b < 8; ++b) {
        acc[b] = w0.x * s[b][0] + w0.y * s[b][1] + w0.z * s[b][2] + w0.w * s[b][3]
               + w1.x * s[b][4] + w1.y * s[b][5] + w1.z * s[b][6] + w1.w * s[b][7];
      }
      #pragma unroll
      for (int m = 32; m; m >>= 1) {
        #pragma unroll
        for (int b = 0; b < 8; ++b) acc[b] += __shfl_xor(acc[b], m, 64);
      }
      if (lane == 0) {
        float bias = lin_b[j];
        int ci = j >> 8, sp = j & 255;
        #pragma unroll
        for (int b = 0; b < 8; ++b)
          smap_bf[(size_t)(b * 256 + sp) * 128 + ci] =
              f2bf(lrelu_s2(acc[b] * LSCALE + bias));
      }
    }
  }
}

// ---------------------------------------------------------------------------
// K2 modconv (verbatim -- verified)
// ---------------------------------------------------------------------------
__global__ __launch_bounds__(512, 2) void modconv_kernel(
    const unsigned short* __restrict__ smap_bf, const short* __restrict__ kb2,
    const float* __restrict__ cw_b, const float* __restrict__ cb_b,
    float* __restrict__ swp) {
  extern __shared__ __align__(16) char dsm[];   // 73984 B
  int par = blockIdx.x, b = blockIdx.y;
  int ph = par >> 1, pw = par & 1;
  int t = threadIdx.x, lane = t & 63, w = t >> 6;
  int q = w >> 1, ch = w & 1;
  int m15 = lane & 15, ksub = lane >> 4;

  for (int c = t; c < 4624; c += 512) {
    int s = c >> 4, cch = c & 15;
    int rr = s / 17, cc = s - rr * 17;
    int gr = rr - 1 + ph, gc = cc - 1 + pw;
    u32x4 v = {0u, 0u, 0u, 0u};
    if ((unsigned)gr < 16u && (unsigned)gc < 16u)
      v = *(const u32x4*)(smap_bf + ((size_t)(b * 256 + gr * 16 + gc) * 128 + cch * 8));
    int phys = (cch + s) & 15;
    *(u32x4*)(dsm + s * 256 + phys * 16) = v;
  }
  __syncthreads();

  const bf16x8* kbv = (const bf16x8*)kb2;
  f32x4 acc[4][8];
  #pragma unroll
  for (int i = 0; i < 4; ++i)
  #pragma unroll
  for (int j = 0; j < 8; ++j) acc[i][j] = (f32x4){0.f, 0.f, 0.f, 0.f};

  for (int s = 0; s < 16; ++s) {
    int t2 = s >> 2, dy2 = t2 >> 1, dx2 = t2 & 1;
    int cch = (s & 3) * 4 + ksub;
    bf16x8 av[4];
    #pragma unroll
    for (int mf = 0; mf < 4; ++mf) {
      int i = q * 4 + mf;
      int ssp = (i + dy2) * 17 + (m15 + dx2);
      int phys = (cch + ssp) & 15;
      av[mf] = *(const bf16x8*)(dsm + ssp * 256 + phys * 16);
    }
    #pragma unroll
    for (int nf = 0; nf < 8; ++nf) {
      bf16x8 bv = kbv[(size_t)((par * 64 + s * 4 + ksub) * 256 + ch * 128 + nf * 16 + m15)];
      #pragma unroll
      for (int mf = 0; mf < 4; ++mf)
        acc[mf][nf] = __builtin_amdgcn_mfma_f32_16x16x32_bf16(av[mf], bv, acc[mf][nf], 0, 0, 0);
    }
  }

  int jbase = ksub * 4;
  #pragma unroll
  for (int nf = 0; nf < 8; ++nf) {
    int co = ch * 128 + nf * 16 + m15;
    float bias = (co < 128) ? cw_b[co] : cb_b[co - 128];
    #pragma unroll
    for (int mf = 0; mf < 4; ++mf) {
      int i = q * 4 + mf;
      #pragma unroll
      for (int r = 0; r < 4; ++r) {
        int px = i * 16 + jbase + r;
        swp[((size_t)(b * 256 + co) * 4 + par) * 256 + px] = acc[mf][nf][r] + bias;
      }
    }
  }
}

// ---------------------------------------------------------------------------
// K3 convt v3 (verbatim r12 -- verified): unfused transposed conv -> 4 parity
// planes bf16, out1[b][pl][co][130][132]; b128 eps epilogue.
// ---------------------------------------------------------------------------
__global__ __launch_bounds__(256, 2) void convt_kernel(
    const unsigned short* __restrict__ xt, const short* __restrict__ kbu,
    unsigned short* __restrict__ out1) {
  __shared__ __align__(16) char smem[34816];   // A-tile 26112; eps 34816
  int cg = blockIdx.x, rp = blockIdx.y, b = blockIdx.z;
  int t = threadIdx.x, lane = t & 63, w = t >> 6;
  int m15 = lane & 15, ksub = lane >> 4;
  int pl = (w + cg + rp) & 3;                  // wave's plane, SIMD-balanced
  int tstart = (pl == 0) ? 0 : 2 + 2 * pl;     // {0,4,6,8}
  int nst = 16 >> ((pl + 1) >> 1);             // {16,8,8,4}

  const char* xtc = (const char*)xt;
  for (int c = t; c < 1632; c += 256) {
    int spos = c >> 4, sub = c & 15;
    int lr = spos / 34, lc = spos - lr * 34;
    int y = 2 * rp - 1 + lr, xg = 32 * cg - 1 + lc;
    f32x4 v = {0.f, 0.f, 0.f, 0.f};
    if ((unsigned)y < 128u && (unsigned)xg < 128u)
      v = *(const f32x4*)(xtc + ((size_t)((b * 128 + y) * 128 + xg)) * 256 + sub * 16);
    int phys = (sub & 8) | ((sub ^ spos) & 7);
    *(f32x4*)(smem + spos * 256 + phys * 16) = v;
  }
  __syncthreads();

  const bf16x8* kbv = (const bf16x8*)kbu;
  f32x4 acc[4][8];
  #pragma unroll
  for (int i = 0; i < 4; ++i)
  #pragma unroll
  for (int j = 0; j < 8; ++j) acc[i][j] = (f32x4){0.f, 0.f, 0.f, 0.f};

  auto LD = [&](int s, bf16x8* av, bf16x8* bv) {
    int tap = tstart + (s >> 2);
    int du = -((0x13 >> tap) & 1);
    int dv = -((0x45 >> tap) & 1);
    int cc = s & 3;
    int c = cc * 4 + ksub;
    #pragma unroll
    for (int mf = 0; mf < 4; ++mf) {
      int spos = ((mf >> 1) + du + 1) * 34 + (mf & 1) * 16 + m15 + dv + 1;
      int phys = (c & 8) | ((c ^ spos) & 7);
      av[mf] = *(const bf16x8*)(smem + spos * 256 + phys * 16);
    }
    int bb = tap * 2048 + cc * 512 + ksub * 128 + m15;
    #pragma unroll
    for (int nf = 0; nf < 8; ++nf) bv[nf] = kbv[bb + nf * 16];
  };
  auto MM = [&](bf16x8* av, bf16x8* bv) {
    __builtin_amdgcn_s_setprio(1);
    #pragma unroll
    for (int nf = 0; nf < 8; ++nf)
    #pragma unroll
    for (int mf = 0; mf < 4; ++mf)
      acc[mf][nf] = __builtin_amdgcn_mfma_f32_16x16x32_bf16(av[mf], bv[nf], acc[mf][nf], 0, 0, 0);
    __builtin_amdgcn_s_setprio(0);
  };

  bf16x8 aA[4], bA[8], aB[4], bB[8];
  LD(0, aA, bA);
  for (int s = 0; s + 2 <= nst; s += 2) {
    LD(s + 1, aB, bB);
    MM(aA, bA);
    if (s + 2 < nst) LD(s + 2, aA, bA);
    MM(aB, bB);
  }

  __syncthreads();
  float* eps = (float*)smem;                   // [(pl*16+pxq)*2+e][68]
  int t63 = t & 63, wpl = t >> 6;
  #pragma unroll
  for (int r2 = 0; r2 < 4; ++r2) {
    #pragma unroll
    for (int e = 0; e < 2; ++e) {
      int nf = r2 * 2 + e;
      #pragma unroll
      for (int mf = 0; mf < 4; ++mf)
        *(f32x4*)(&eps[(((pl * 16 + mf * 4 + ksub) * 2 + e) * 68) + m15 * 4]) = acc[mf][nf];
    }
    __syncthreads();
    #pragma unroll
    for (int k = 0; k < 8; ++k) {
      int slot = k * 64 + t63;                 // [e:1][co16:4][pr:1][ch:3]
      int er = slot >> 8, co16 = (slot >> 4) & 15, pr = (slot >> 3) & 1, ch = slot & 7;
      f32x4 v = *(const f32x4*)(&eps[(((wpl * 16 + pr * 8 + ch) * 2 + er) * 68) + co16 * 4]);
      u32x2 o;
      o.x = (unsigned int)f2bf(v[0]) | ((unsigned int)f2bf(v[1]) << 16);
      o.y = (unsigned int)f2bf(v[2]) | ((unsigned int)f2bf(v[3]) << 16);
      int co = (r2 * 2 + er) * 16 + co16;
      int r = 2 * rp + pr;
      size_t ob = (((size_t)(b * 4 + wpl) * 128 + co) * 130 + r) * 132
                + 32 * cg + ch * 4;
      if (cg < 4 || ch == 0) *(u32x2*)(out1 + ob) = o;
    }
    __syncthreads();
  }
}

// ---------------------------------------------------------------------------
// K4/K5 blur v6 (verbatim r13 -- verified): single-stage stencil, fused
// u32x4 staging, NT stores (PASS1 only), NORMAL loads (out1 is L3-resident).
// ---------------------------------------------------------------------------
template <int PASS>
__global__ __launch_bounds__(256) void blur_kernel(
    const unsigned short* __restrict__ out1, float* __restrict__ part,
    const float* __restrict__ swp, float* __restrict__ dout) {
  __shared__ __align__(16) unsigned short S[18][4][144];
  __shared__ float lsw[4][32], lsb[4][32];
  __shared__ float msh[2];
  __shared__ float rb2[8];
  int g = blockIdx.x, co = blockIdx.y, b = blockIdx.z;
  int t = threadIdx.x, lane = t & 63, wid = t >> 6;
  int bc = b * 128 + co;

  if (PASS == 1) {
    if (t == 0) {
      float a1 = 0.f, a2 = 0.f;
      #pragma unroll
      for (int i = 0; i < 8; ++i) {
        a1 += part[((size_t)bc * 8 + i) * 2];
        a2 += part[((size_t)bc * 8 + i) * 2 + 1];
      }
      float mean = a1 * (1.f / 65536.f);
      float var = a2 * (1.f / 65536.f) - mean * mean;
      msh[0] = mean; msh[1] = rsqrtf(var + 1e-5f);
    }
    {
      int which = t >> 7;
      int par = (t >> 5) & 3;
      int idx = t & 31;
      int hrow = idx >> 4, wcol = idx & 15;
      int px2 = (2 * g + hrow) * 16 + wcol;
      float v = swp[((size_t)(b * 256 + which * 128 + co) * 4 + par) * 256 + px2];
      if (which == 0) lsw[par][idx] = v; else lsb[par][idx] = v;
    }
  }

  // ---- stage S: rows lr 0..17, 4 planes; fused 16B load + 16B LDS write ----
  int rbase = 16 * g - 1;
  for (int i = t; i < 1152; i += 256) {
    int rid = i >> 4, ch = i & 15;
    int lr = rid >> 2, pl = rid & 3;
    int r = rbase + lr;
    u32x4 v = {0u, 0u, 0u, 0u};
    if (r >= 0)
      v = *(const u32x4*)(out1 + ((size_t)((b * 4 + pl) * 128 + co) * 130 + r) * 132 + ch * 8);
    *(u32x4*)(&S[lr][pl][8 + ch * 8]) = v;
  }
  if (t < 72) {
    int lr = t >> 2, pl = t & 3;
    int r = rbase + lr;
    u32x2 v = {0u, 0u};
    if (r >= 0)
      v = *(const u32x2*)(out1 + ((size_t)((b * 4 + pl) * 128 + co) * 130 + r) * 132 + 128);
    *(u32x2*)(&S[lr][pl][136]) = v;
  }
  if (t >= 128 && t < 200) {
    int q = t - 128;
    *(unsigned int*)(&S[q >> 2][q & 3][6]) = 0u;
  }
  __syncthreads();

  float mean = 0.f, rstd = 0.f;
  if (PASS == 1) { mean = msh[0]; rstd = msh[1]; }

  int rg = t >> 5, cg = t & 31;
  int sr = 2 * rg;
  unsigned int Eu[2][3][4], Ou[2][4][4];
  #pragma unroll
  for (int cp = 0; cp < 2; ++cp) {
    #pragma unroll
    for (int rr = 0; rr < 3; ++rr) {
      const unsigned int* p = (const unsigned int*)&S[sr + 1 + rr][cp][0];
      #pragma unroll
      for (int j = 0; j < 4; ++j) Eu[cp][rr][j] = p[2 * cg + 3 + j];
    }
    #pragma unroll
    for (int rr = 0; rr < 4; ++rr) {
      const unsigned int* p = (const unsigned int*)&S[sr + rr][2 + cp][0];
      #pragma unroll
      for (int j = 0; j < 4; ++j) Ou[cp][rr][j] = p[2 * cg + 3 + j];
    }
  }

  float s1 = 0.f, s2 = 0.f;
  #pragma unroll
  for (int k = 0; k < 4; ++k) {
    const int a = (k + 1) >> 1;
    float Tc[2][6];
    #pragma unroll
    for (int cp = 0; cp < 2; ++cp)
    #pragma unroll
    for (int rel = 0; rel < 6; ++rel) {
      float v;
      if ((k & 1) == 0)
        v = EX(Ou[cp][a], rel) + 3.f * EX(Eu[cp][a], rel)
          + 3.f * EX(Ou[cp][a + 1], rel) + EX(Eu[cp][a + 1], rel);
      else
        v = EX(Eu[cp][a - 1], rel) + 3.f * EX(Ou[cp][a], rel)
          + 3.f * EX(Eu[cp][a], rel) + EX(Ou[cp][a + 1], rel);
      Tc[cp][rel] = v;
    }
    float o8[8];
    #pragma unroll
    for (int i = 0; i < 4; ++i) {
      float ve = ((Tc[1][i] + Tc[0][i + 2]) + 3.f * (Tc[0][i + 1] + Tc[1][i + 1])) * 0.0625f;
      float vo = ((Tc[0][i + 1] + Tc[1][i + 2]) + 3.f * (Tc[1][i + 1] + Tc[0][i + 2])) * 0.0625f;
      if (PASS == 0) {
        s1 += ve + vo; s2 += ve * ve + vo * vo;
      } else {
        o8[2 * i] = ve; o8[2 * i + 1] = vo;
      }
    }
    if (PASS == 1) {
      int hl = 4 * rg + k;
      int h = 32 * g + hl;
      int par = ((hl >> 3) & 1) * 2 + (cg & 1);
      int lidx = ((hl >> 4) & 1) * 16 + (cg >> 1);
      float f1 = (1.f + 0.3f * lsw[par][lidx]) * rstd;
      float f0 = 0.3f * lsb[par][lidx] - mean * f1;
      f32x4 oA = {o8[0] * f1 + f0, o8[1] * f1 + f0, o8[2] * f1 + f0, o8[3] * f1 + f0};
      f32x4 oB = {o8[4] * f1 + f0, o8[5] * f1 + f0, o8[6] * f1 + f0, o8[7] * f1 + f0};
      float* op = dout + ((size_t)bc * 256 + h) * 256 + 8 * cg;
      __builtin_nontemporal_store(oA, (f32x4*)op);
      __builtin_nontemporal_store(oB, (f32x4*)(op + 4));
    }
  }

  if (PASS == 0) {
    #pragma unroll
    for (int m = 32; m; m >>= 1) { s1 += __shfl_xor(s1, m, 64); s2 += __shfl_xor(s2, m, 64); }
    if (lane == 0) { rb2[wid * 2] = s1; rb2[wid * 2 + 1] = s2; }
    __syncthreads();
    if (t == 0) {
      part[((size_t)bc * 8 + g) * 2]     = rb2[0] + rb2[2] + rb2[4] + rb2[6];
      part[((size_t)bc * 8 + g) * 2 + 1] = rb2[1] + rb2[3] + rb2[5] + rb2[7];
    }
  }
}

extern "C" void kernel_launch(void* const* d_in, const int* in_sizes, int n_in,
                              void* d_out, int out_size, void* d_ws, size_t ws_size,
                              hipStream_t stream) {
  const float* x      = (const float*)d_in[0];
  const float* style  = (const float*)d_in[1];
  const float* weight = (const float*)d_in[2];
  const float* lin_w  = (const float*)d_in[3];
  const float* lin_b  = (const float*)d_in[4];
  const float* cw_w   = (const float*)d_in[5];
  const float* cw_b   = (const float*)d_in[6];
  const float* cb_w   = (const float*)d_in[7];
  const float* cb_b   = (const float*)d_in[8];
  float* out = (float*)d_out;
  char* ws = (char*)d_ws;

  short*          kbu     = (short*)(ws);                     //   294,912
  short*          kb2     = (short*)(ws + 294912);            // 1,048,576
  unsigned short* xt      = (unsigned short*)(ws + 1343488);  // 33,554,432
  unsigned short* smap_bf = (unsigned short*)(ws + 34897920); //   524,288
  float*          swp     = (float*)(ws + 35422208);          // 8,388,608
  float*          part    = (float*)(ws + 43810816);          //   131,072
  unsigned short* out1    = (unsigned short*)(ws + 43941888); // 140,574,720 (end 184.5MB)

  prep_all<<<dim3(4160), dim3(256), 0, stream>>>(
      weight, cw_w, cb_w, x, style, lin_w, lin_b, kbu, kb2, xt, smap_bf);
  modconv_kernel<<<dim3(4, 8), dim3(512), 73984, stream>>>(smap_bf, kb2, cw_b, cb_b, swp);
  convt_kernel<<<dim3(5, 65, 8), dim3(256), 0, stream>>>(xt, kbu, out1);
  blur_kernel<0><<<dim3(8, 128, 8), dim3(256), 0, stream>>>(out1, part, swp, out);
  blur_kernel<1><<<dim3(8, 128, 8), dim3(256), 0, stream>>>(out1, part, swp, out);
}